// Round 8
// baseline (704.461 us; speedup 1.0000x reference)
//
#include <hip/hip_runtime.h>
#include <hip/hip_bf16.h>
#include <math.h>

typedef unsigned short u16;
typedef unsigned int u32;
typedef short s8v __attribute__((ext_vector_type(8)));   // 8 x bf16 bits (4 VGPRs)
typedef float f4v __attribute__((ext_vector_type(4)));   // 16x16 MFMA accumulator
typedef float f16v __attribute__((ext_vector_type(16))); // 32x32 MFMA accumulator
typedef u32 u4v __attribute__((ext_vector_type(4)));
typedef u32 u2v __attribute__((ext_vector_type(2)));

#define D_MODEL 1024
#define DIMFF   4096
#define SEQ     2048
#define TOKENS  8192   // B*T

// 0.125 (1/sqrt(dh)) * log2(e): folded into Q at the QKV epilogue
#define QSCALE 0.18033688011112042f

static __device__ __forceinline__ u16 f2bf(float f) {
    unsigned int u = __builtin_bit_cast(unsigned int, f);
    unsigned int lsb = (u >> 16) & 1u;
    u += 0x7fffu + lsb;                 // round-to-nearest-even
    return (u16)(u >> 16);
}

static __device__ __forceinline__ float gelu_fast(float z) {
    float z2 = z * z;
    float p  = fmaf(z2, -0.1029472255f, -2.3021867892f);  // -2*log2e*sqrt(2/pi)*{0.044715, 1}
    float e  = __builtin_amdgcn_exp2f(z * p);
    return z * __builtin_amdgcn_rcpf(1.0f + e);
}

// async global->LDS, 16B per lane; lds dest = wave-uniform base + lane*16
static __device__ __forceinline__ void gl2lds16(const u16* g, u16* l) {
    __builtin_amdgcn_global_load_lds(
        (__attribute__((address_space(1))) void*)(void*)g,
        (__attribute__((address_space(3))) void*)l, 16, 0, 0);
}

// raw barrier (no compiler vmcnt(0) drain like __syncthreads) + motion fences
static __device__ __forceinline__ void bar() {
    __builtin_amdgcn_sched_barrier(0);
    asm volatile("" ::: "memory");
    __builtin_amdgcn_s_barrier();
    asm volatile("" ::: "memory");
    __builtin_amdgcn_sched_barrier(0);
}

template<int N> static __device__ __forceinline__ void vwait() {
    if constexpr (N == 12)      asm volatile("s_waitcnt vmcnt(12)" ::: "memory");
    else if constexpr (N == 8)  asm volatile("s_waitcnt vmcnt(8)" ::: "memory");
    else                        asm volatile("s_waitcnt vmcnt(0)" ::: "memory");
}

// ---------------- fp32 -> bf16 convert, all 4 weights in one launch ----------------
#define N4_QKV  786432   // 3072*1024/4
#define N4_WO   262144   // 1024*1024/4
#define N4_FC   1048576  // 4096*1024/4
__global__ __launch_bounds__(256) void cvt_all_kernel(const float* __restrict__ s0,
                                                      const float* __restrict__ s1,
                                                      const float* __restrict__ s2,
                                                      const float* __restrict__ s3,
                                                      u16* __restrict__ dst) {
    int i = blockIdx.x * 256 + threadIdx.x;
    const float* src; int j;
    if (i < N4_QKV)                    { src = s0; j = i; }
    else if (i < N4_QKV + N4_WO)       { src = s1; j = i - N4_QKV; }
    else if (i < N4_QKV + N4_WO + N4_FC) { src = s2; j = i - N4_QKV - N4_WO; }
    else                               { src = s3; j = i - N4_QKV - N4_WO - N4_FC; }
    float4 v = ((const float4*)src)[j];
    ushort4 o;
    o.x = f2bf(v.x); o.y = f2bf(v.y); o.z = f2bf(v.z); o.w = f2bf(v.w);
    ((ushort4*)dst)[i] = o;
}

// ---------------- LayerNorm: fp32 in -> bf16 out ----------------
__global__ __launch_bounds__(256) void ln_kernel(const float* __restrict__ x,
                                                 const float* __restrict__ scale,
                                                 const float* __restrict__ bias,
                                                 u16* __restrict__ out) {
    int row = blockIdx.x;
    int t = threadIdx.x;
    const float* xr = x + (size_t)row * D_MODEL;
    float4 v = ((const float4*)xr)[t];
    float s  = v.x + v.y + v.z + v.w;
    float ss = v.x*v.x + v.y*v.y + v.z*v.z + v.w*v.w;
    #pragma unroll
    for (int off = 1; off < 64; off <<= 1) {
        s  += __shfl_xor(s, off);
        ss += __shfl_xor(ss, off);
    }
    __shared__ float red[8];
    int wave = t >> 6, lane = t & 63;
    if (lane == 0) { red[wave] = s; red[4 + wave] = ss; }
    __syncthreads();
    float S  = red[0] + red[1] + red[2] + red[3];
    float SS = red[4] + red[5] + red[6] + red[7];
    float mu  = S * (1.0f / D_MODEL);
    float var = SS * (1.0f / D_MODEL) - mu * mu;
    float r = rsqrtf(var + 1e-5f);
    float4 sc = ((const float4*)scale)[t];
    float4 bi = ((const float4*)bias)[t];
    ushort4 o;
    o.x = f2bf((v.x - mu) * r * sc.x + bi.x);
    o.y = f2bf((v.y - mu) * r * sc.y + bi.y);
    o.z = f2bf((v.z - mu) * r * sc.z + bi.z);
    o.w = f2bf((v.w - mu) * r * sc.w + bi.w);
    ((ushort4*)(out + (size_t)row * D_MODEL))[t] = o;
}

// ---------------- bf16 MFMA GEMM: A direct-to-reg, B-only LDS ring ----------------
// 128x128 tile, BK=64, 4 waves (2x2, wave tile 64x64, acc[4][4]).
// A-fragments load GLOBAL->VGPR directly (per-lane addresses, no LDS round
// trip -- A is read by only 2 waves, LDS staging bought no sharing), reg-dbuf
// one K-tile ahead; compiler inserts the precise vmcnt for the reg consumers.
// B (shared W panel) stays in a 3-deep 16KB-slot LDS ring (48KB total -> 2
// independent blocks/CU). Per K-tile, ONE barrier: issue A(t+1)->regs, stage
// B(t+2) (4 gl2lds), ds_read B(t) frags, lgkm(0), vwait<12> (leaves exactly
// this tile's 8 A-loads + 4 stages in flight -> A(t) and B(t+1) landed),
// 32 MFMA (ks-outer, dep distance 16), bar.
// Ring hazard: stage at t targets slot (t+2)%3, whose readers ran at t-1 and
// completed before t-1's end barrier -> safe. LDS traffic cut ~3x vs r7.
// Swizzle (128B rows, verified): slot s of row r holds chunk s^(r&7).
// 2-D XCD remap: bm = xcd*8 + (li&7), bn = li>>3 (64 bm = 8 XCD x 8).
template<int MODE>
__global__ __launch_bounds__(256, 2) void gemm_kernel(
        const u16* __restrict__ A, const u16* __restrict__ W,
        const float* __restrict__ bias, const float* __restrict__ res,
        void* __restrict__ outp, void* __restrict__ out2, int M, int N, int K) {
    constexpr int BN_ = 128, BK = 64;
    constexpr int BSZ = BN_ * BK;          // u16: 8192 (16KB)
    __shared__ __attribute__((aligned(16))) u16 Bs[3][BSZ];

    int t = threadIdx.x;
    int lane = t & 63, w = t >> 6;         // 4 waves
    int lc = lane & 15, lr = lane >> 4;
    int xcd = blockIdx.x & 7, li = blockIdx.x >> 3;
    int bm = xcd * 8 + (li & 7), bn = li >> 3;
    int m0 = bm * 128, n0 = bn * BN_;
    int wm = (w & 1) * 64, wn = (w >> 1) * 64;

    // per-lane A base: row m0+wm+lc, 16B chunk lr (of 8 per 64-col K-tile)
    const u16* Alane = A + (size_t)(m0 + wm + lc) * K + lr * 8;
    const u16* Bbase = W + (size_t)n0 * K;

    // B stage descriptors: 16 ops of 8 rows x 8 chunks; pre-swizzled source
    int boff[4], bldo[4];
    #pragma unroll
    for (int n = 0; n < 4; ++n) {
        int opid = n * 4 + w;
        int row = opid * 8 + (lane >> 3);
        boff[n] = row * K + ((lane & 7) ^ (row & 7)) * 8;
        bldo[n] = opid * 512;
    }

    const int NK = K / BK;
    const int NKm1 = NK - 1;
    // prologue: stage B(0)->slot0, B(1)->slot1; load A(0) frags
    #pragma unroll
    for (int n = 0; n < 4; ++n) gl2lds16(Bbase + boff[n], &Bs[0][bldo[n]]);
    #pragma unroll
    for (int n = 0; n < 4; ++n) gl2lds16(Bbase + boff[n] + 64, &Bs[1][bldo[n]]);
    f4v acc[4][4] = {};
    s8v afA[4][2], afB[4][2], bf[4][2];
    #pragma unroll
    for (int i = 0; i < 4; ++i)
        #pragma unroll
        for (int ks = 0; ks < 2; ++ks)
            afA[i][ks] = *(const s8v*)&Alane[(size_t)i * 16 * K + ks * 32];
    vwait<0>();
    bar();

    const u16* Br = Bs[0];
    u16* Bn = (u16*)Bs[1];
    u16* Bss = (u16*)Bs[2];

// per-K-tile: A(T+1)->AFN (global, reg); stage B(T+2); ds_read bf(T);
// lgkm(0)+vwait<12>; 32 MFMA from AFC; one barrier; rotate ring.
#define GSTEP(T, AFC, AFN)                                                    \
    {                                                                         \
        int tn = (T) + 1; if (tn > NKm1) tn = NKm1;                           \
        int ts = (T) + 2; if (ts > NKm1) ts = NKm1;                           \
        _Pragma("unroll")                                                     \
        for (int i = 0; i < 4; ++i)                                           \
            _Pragma("unroll")                                                 \
            for (int ks = 0; ks < 2; ++ks)                                    \
                AFN[i][ks] = *(const s8v*)&Alane[(size_t)i * 16 * K + ks * 32 + (size_t)tn * 64]; \
        _Pragma("unroll")                                                     \
        for (int n = 0; n < 4; ++n)                                           \
            gl2lds16(Bbase + boff[n] + (size_t)ts * 64, Bss + bldo[n]);       \
        _Pragma("unroll")                                                     \
        for (int j = 0; j < 4; ++j) {                                         \
            int brow = wn + j * 16 + lc;                                      \
            _Pragma("unroll")                                                 \
            for (int ks = 0; ks < 2; ++ks)                                    \
                bf[j][ks] = *(const s8v*)&Br[brow * 64 + ((ks * 4 + lr) ^ (brow & 7)) * 8]; \
        }                                                                     \
        asm volatile("s_waitcnt lgkmcnt(0)" ::: "memory");                    \
        vwait<12>();                                                          \
        __builtin_amdgcn_sched_barrier(0);                                    \
        __builtin_amdgcn_s_setprio(1);                                        \
        _Pragma("unroll")                                                     \
        for (int ks = 0; ks < 2; ++ks)                                        \
            _Pragma("unroll")                                                 \
            for (int i = 0; i < 4; ++i)                                       \
                _Pragma("unroll")                                             \
                for (int j = 0; j < 4; ++j) {                                 \
                    if constexpr (MODE == 4)                                  \
                        acc[i][j] = __builtin_amdgcn_mfma_f32_16x16x32_bf16(AFC[i][ks], bf[j][ks], acc[i][j], 0, 0, 0); \
                    else                                                      \
                        acc[i][j] = __builtin_amdgcn_mfma_f32_16x16x32_bf16(bf[j][ks], AFC[i][ks], acc[i][j], 0, 0, 0); \
                }                                                             \
        __builtin_amdgcn_s_setprio(0);                                        \
        bar();                                                                \
        u16* tmpB = (u16*)Br; Br = Bn; Bn = Bss; Bss = tmpB;                  \
    }

    for (int kt = 0; kt < NK; kt += 2) {
        GSTEP(kt,     afA, afB)
        GSTEP(kt + 1, afB, afA)
    }
#undef GSTEP

    if constexpr (MODE == 4) {
        #pragma unroll
        for (int i = 0; i < 4; ++i) {
            #pragma unroll
            for (int j = 0; j < 4; ++j) {
                int col = n0 + wn + j * 16 + lc;
                int colbase = n0 + wn + j * 16;   // wave-uniform segment select
                if (colbase < 2048) {
                    float sc = (colbase < 1024) ? QSCALE : 1.0f;
                    #pragma unroll
                    for (int r = 0; r < 4; ++r) {
                        int row = m0 + wm + i * 16 + lr * 4 + r;
                        ((u16*)outp)[(size_t)row * 2048 + col] = f2bf(acc[i][j][r] * sc);
                    }
                } else {
                    // V: write transposed to vt[bh*64+d][t], 4 consecutive t packed
                    int dlin = col - 2048;
                    int h = dlin >> 6, dd = dlin & 63;
                    int trow = m0 + wm + i * 16 + lr * 4;
                    int bb = trow >> 11, tt = trow & 2047;
                    int bh = bb * 16 + h;
                    ushort4 vv;
                    vv.x = f2bf(acc[i][j][0]); vv.y = f2bf(acc[i][j][1]);
                    vv.z = f2bf(acc[i][j][2]); vv.w = f2bf(acc[i][j][3]);
                    *(ushort4*)&((u16*)out2)[((size_t)bh * 64 + dd) * SEQ + tt] = vv;
                }
            }
        }
    } else {
        // swapped layout: lane lc owns row = wm+i*16+lc, 4 consecutive cols at lr*4
        #pragma unroll
        for (int j = 0; j < 4; ++j) {
            int colb = n0 + wn + j * 16 + lr * 4;
            float4 b4;
            if constexpr (MODE != 1) b4 = *(const float4*)&bias[colb];
            #pragma unroll
            for (int i = 0; i < 4; ++i) {
                int row = m0 + wm + i * 16 + lc;
                size_t idx = (size_t)row * N + colb;
                f4v a = acc[i][j];
                if constexpr (MODE == 2) {
                    ushort4 o;
                    o.x = f2bf(gelu_fast(a[0] + b4.x));
                    o.y = f2bf(gelu_fast(a[1] + b4.y));
                    o.z = f2bf(gelu_fast(a[2] + b4.z));
                    o.w = f2bf(gelu_fast(a[3] + b4.w));
                    *(ushort4*)&((u16*)outp)[idx] = o;
                } else {
                    float4 rr = *(const float4*)&res[idx];
                    float4 o;
                    if constexpr (MODE == 3) {
                        o.x = rr.x + a[0] + b4.x; o.y = rr.y + a[1] + b4.y;
                        o.z = rr.z + a[2] + b4.z; o.w = rr.w + a[3] + b4.w;
                    } else {
                        o.x = rr.x + a[0]; o.y = rr.y + a[1];
                        o.z = rr.z + a[2]; o.w = rr.w + a[3];
                    }
                    *(float4*)&((float*)outp)[idx] = o;
                }
            }
        }
    }
}

// ---------------- flash attention, 32x32x16 MFMA (unchanged from r4) ----------------
__global__ __launch_bounds__(256) void attn_kernel(const u16* __restrict__ qk,
                                                   const u16* __restrict__ vt,
                                                   u16* __restrict__ out) {
    __shared__ __attribute__((aligned(16))) u16 Ks[64 * 64];   // [key][d], swizzled chunks
    __shared__ __attribute__((aligned(16))) u16 Vts[64 * 64];  // [d][key], swizzled chunks
    __shared__ float l_s[128];
    int t = threadIdx.x, lane = t & 63, w = t >> 6;
    int l31 = lane & 31, hi = lane >> 5;
    int blk = blockIdx.x;
    int bh = blk & 63, qt = blk >> 6;    // XCD swizzle: same head -> same XCD
    int b = bh >> 4, h = bh & 15;
    size_t tok0 = (size_t)b * SEQ;
    int q0 = qt * 128;

    // Q B-operand frags in registers: B[n=q=l31][k=hi*8+j], 4 d-chunks of 16
    s8v bq[4];
    {
        const u16* qp = qk + (tok0 + q0 + w * 32 + l31) * 2048 + h * 64 + hi * 8;
        #pragma unroll
        for (int dch = 0; dch < 4; ++dch) bq[dch] = *(const s8v*)(qp + dch * 16);
    }
    f16v o[2] = {};
    float lp = 0.f;

    int srow[2], scg[2];
    #pragma unroll
    for (int n = 0; n < 2; ++n) {
        int chunk = (w * 2 + n) * 64 + lane;
        srow[n] = chunk >> 3;
        scg[n]  = ((chunk & 7) ^ (srow[n] & 7)) * 8;
    }
    const u16* vbase = vt + (size_t)bh * 64 * SEQ;

    for (int kt = 0; kt < SEQ / 64; ++kt) {
        #pragma unroll
        for (int n = 0; n < 2; ++n) {
            gl2lds16(&qk[(tok0 + kt * 64 + srow[n]) * 2048 + 1024 + h * 64 + scg[n]],
                     &Ks[(w * 2 + n) * 512]);
            gl2lds16(&vbase[(size_t)srow[n] * SEQ + kt * 64 + scg[n]],
                     &Vts[(w * 2 + n) * 512]);
        }
        __syncthreads();

        // S^T = K Q'^T : two 32-key blocks; D: lane=q, reg r -> key rr+8g+4hi
        f16v s_[2] = {};
        #pragma unroll
        for (int kb = 0; kb < 2; ++kb)
            #pragma unroll
            for (int dch = 0; dch < 4; ++dch) {
                s8v ak = *(const s8v*)&Ks[(kb * 32 + l31) * 64 + ((dch * 2 + hi) ^ (l31 & 7)) * 8];
                s_[kb] = __builtin_amdgcn_mfma_f32_32x32x16_bf16(ak, bq[dch], s_[kb], 0, 0, 0);
            }

        // p = 2^s (Schraudolph bits) -> packed bf16 pairs in registers
        u2v pk[2][4];
        #pragma unroll
        for (int kb = 0; kb < 2; ++kb)
            #pragma unroll
            for (int g = 0; g < 4; ++g) {
                u32 ib[4];
                #pragma unroll
                for (int rr = 0; rr < 4; ++rr) {
                    ib[rr] = (u32)fmaf(s_[kb][g * 4 + rr], 8388608.0f, 1064992506.0f);
                    lp += __builtin_bit_cast(float, ib[rr]);
                }
                pk[kb][g][0] = __builtin_amdgcn_perm(ib[1], ib[0], 0x07060302);
                pk[kb][g][1] = __builtin_amdgcn_perm(ib[3], ib[2], 0x07060302);
            }

        // O += P V : per ch, 2 permlane32_swap deliver both A-frag halves
        #pragma unroll
        for (int ch = 0; ch < 4; ++ch) {
            int kb = ch >> 1, a2 = (ch & 1) * 2;
            u2v sx = __builtin_amdgcn_permlane32_swap(pk[kb][a2][0], pk[kb][a2 + 1][0], false, false);
            u2v sy = __builtin_amdgcn_permlane32_swap(pk[kb][a2][1], pk[kb][a2 + 1][1], false, false);
            u4v tmp; tmp.x = sx[0]; tmp.y = sy[0]; tmp.z = sx[1]; tmp.w = sy[1];
            s8v ap = __builtin_bit_cast(s8v, tmp);
            #pragma unroll
            for (int dblk = 0; dblk < 2; ++dblk) {
                s8v bv = *(const s8v*)&Vts[(dblk * 32 + l31) * 64 + ((ch * 2 + hi) ^ (l31 & 7)) * 8];
                o[dblk] = __builtin_amdgcn_mfma_f32_32x32x16_bf16(ap, bv, o[dblk], 0, 0, 0);
            }
        }
        __syncthreads();   // guard Ks/Vts overwrite by next tile's staging
    }

    lp += __shfl_xor(lp, 32);
    l_s[w * 32 + l31] = 1.0f / lp;
    #pragma unroll
    for (int r = 0; r < 16; ++r) {
        int qrl = (r & 3) + 8 * (r >> 2) + 4 * hi;
        float linv = l_s[w * 32 + qrl];
        size_t row = tok0 + q0 + w * 32 + qrl;
        #pragma unroll
        for (int dblk = 0; dblk < 2; ++dblk)
            out[row * 1024 + h * 64 + dblk * 32 + l31] = f2bf(o[dblk][r] * linv);
    }
}

// ---------------- launch ----------------
extern "C" void kernel_launch(void* const* d_in, const int* in_sizes, int n_in,
                              void* d_out, int out_size, void* d_ws, size_t ws_size,
                              hipStream_t stream) {
    const float* x      = (const float*)d_in[0];
    const float* ln1_s  = (const float*)d_in[1];
    const float* ln1_b  = (const float*)d_in[2];
    const float* qkv_w  = (const float*)d_in[3];
    const float* out_w  = (const float*)d_in[4];
    const float* ln2_s  = (const float*)d_in[5];
    const float* ln2_b  = (const float*)d_in[6];
    const float* fc1_w  = (const float*)d_in[7];
    const float* fc1_b  = (const float*)d_in[8];
    const float* fc2_w  = (const float*)d_in[9];
    const float* fc2_b  = (const float*)d_in[10];
    float* out = (float*)d_out;

    char* ws = (char*)d_ws;
    size_t off = 0;
    auto alloc = [&](size_t bytes) -> void* {
        void* p = ws + off;
        off += (bytes + 255) & ~(size_t)255;
        return p;
    };
    u16* wq  = (u16*)alloc((size_t)3072 * 1024 * 2);   // wq|wo|w1|w2 contiguous
    u16* wo  = (u16*)alloc((size_t)1024 * 1024 * 2);
    u16* w1  = (u16*)alloc((size_t)4096 * 1024 * 2);
    u16* w2  = (u16*)alloc((size_t)1024 * 4096 * 2);
    u16* h1  = (u16*)alloc((size_t)TOKENS * 1024 * 2);   // aliased later as attn_out
    u16* qk  = (u16*)alloc((size_t)TOKENS * 2048 * 2);   // Q' | K ; aliased later as h2
    float* x2 = (float*)alloc((size_t)TOKENS * 1024 * 4);
    u16* g   = (u16*)alloc((size_t)TOKENS * 4096 * 2);
    u16* attn_out = h1;        // h1 dead after QKV GEMM
    u16* h2       = qk;        // qk dead after attention
    u16* vt       = (u16*)x2;  // vt (16MB) dead before x2 (32MB) is written
    (void)wo; (void)w1; (void)w2;

    cvt_all_kernel<<<(N4_QKV + N4_WO + 2 * N4_FC) / 256, 256, 0, stream>>>(
        qkv_w, out_w, fc1_w, fc2_w, wq);

    // LN1
    ln_kernel<<<TOKENS, 256, 0, stream>>>(x, ln1_s, ln1_b, h1);
    // QKV projection: 128x128 tiles (grid 1536)
    gemm_kernel<4><<<(TOKENS / 128) * (3072 / 128), 256, 0, stream>>>(
        h1, wq, nullptr, nullptr, qk, vt, TOKENS, 3072, 1024);
    // attention
    attn_kernel<<<64 * 16, 256, 0, stream>>>(qk, vt, attn_out);
    // out projection + residual (grid 512)
    gemm_kernel<1><<<(TOKENS / 128) * (1024 / 128), 256, 0, stream>>>(
        attn_out, wo, nullptr, x, x2, nullptr, TOKENS, 1024, 1024);
    // LN2
    ln_kernel<<<TOKENS, 256, 0, stream>>>(x2, ln2_s, ln2_b, h2);
    // FC1 + bias + fast GELU (grid 2048)
    gemm_kernel<2><<<(TOKENS / 128) * (DIMFF / 128), 256, 0, stream>>>(
        h2, w1, fc1_b, nullptr, g, nullptr, TOKENS, DIMFF, 1024);
    // FC2 + bias + residual (grid 512)
    gemm_kernel<3><<<(TOKENS / 128) * (1024 / 128), 256, 0, stream>>>(
        g, w2, fc2_b, x2, out, nullptr, TOKENS, 1024, DIMFF);
}

// Round 9
// 503.093 us; speedup vs baseline: 1.4003x; 1.4003x over previous
//
#include <hip/hip_runtime.h>
#include <hip/hip_bf16.h>
#include <math.h>

typedef unsigned short u16;
typedef unsigned int u32;
typedef short s8v __attribute__((ext_vector_type(8)));   // 8 x bf16 bits (4 VGPRs)
typedef float f4v __attribute__((ext_vector_type(4)));   // 16x16 MFMA accumulator
typedef float f16v __attribute__((ext_vector_type(16))); // 32x32 MFMA accumulator
typedef u32 u4v __attribute__((ext_vector_type(4)));
typedef u32 u2v __attribute__((ext_vector_type(2)));

#define D_MODEL 1024
#define DIMFF   4096
#define SEQ     2048
#define TOKENS  8192   // B*T

// 0.125 (1/sqrt(dh)) * log2(e): folded into Q at the QKV epilogue
#define QSCALE 0.18033688011112042f

static __device__ __forceinline__ u16 f2bf(float f) {
    unsigned int u = __builtin_bit_cast(unsigned int, f);
    unsigned int lsb = (u >> 16) & 1u;
    u += 0x7fffu + lsb;                 // round-to-nearest-even
    return (u16)(u >> 16);
}

static __device__ __forceinline__ float gelu_fast(float z) {
    float z2 = z * z;
    float p  = fmaf(z2, -0.1029472255f, -2.3021867892f);  // -2*log2e*sqrt(2/pi)*{0.044715, 1}
    float e  = __builtin_amdgcn_exp2f(z * p);
    return z * __builtin_amdgcn_rcpf(1.0f + e);
}

// async global->LDS, 16B per lane; lds dest = wave-uniform base + lane*16
static __device__ __forceinline__ void gl2lds16(const u16* g, u16* l) {
    __builtin_amdgcn_global_load_lds(
        (__attribute__((address_space(1))) void*)(void*)g,
        (__attribute__((address_space(3))) void*)l, 16, 0, 0);
}

// raw barrier (no compiler vmcnt(0) drain like __syncthreads) + motion fences
static __device__ __forceinline__ void bar() {
    __builtin_amdgcn_sched_barrier(0);
    asm volatile("" ::: "memory");
    __builtin_amdgcn_s_barrier();
    asm volatile("" ::: "memory");
    __builtin_amdgcn_sched_barrier(0);
}

template<int N> static __device__ __forceinline__ void vwait() {
    if constexpr (N == 8)       asm volatile("s_waitcnt vmcnt(8)" ::: "memory");
    else if constexpr (N == 12) asm volatile("s_waitcnt vmcnt(12)" ::: "memory");
    else                        asm volatile("s_waitcnt vmcnt(0)" ::: "memory");
}

// ---------------- fp32 -> bf16 convert, all 4 weights in one launch ----------------
#define N4_QKV  786432   // 3072*1024/4
#define N4_WO   262144   // 1024*1024/4
#define N4_FC   1048576  // 4096*1024/4
__global__ __launch_bounds__(256) void cvt_all_kernel(const float* __restrict__ s0,
                                                      const float* __restrict__ s1,
                                                      const float* __restrict__ s2,
                                                      const float* __restrict__ s3,
                                                      u16* __restrict__ dst) {
    int i = blockIdx.x * 256 + threadIdx.x;
    const float* src; int j;
    if (i < N4_QKV)                    { src = s0; j = i; }
    else if (i < N4_QKV + N4_WO)       { src = s1; j = i - N4_QKV; }
    else if (i < N4_QKV + N4_WO + N4_FC) { src = s2; j = i - N4_QKV - N4_WO; }
    else                               { src = s3; j = i - N4_QKV - N4_WO - N4_FC; }
    float4 v = ((const float4*)src)[j];
    ushort4 o;
    o.x = f2bf(v.x); o.y = f2bf(v.y); o.z = f2bf(v.z); o.w = f2bf(v.w);
    ((ushort4*)dst)[i] = o;
}

// ---------------- LayerNorm: fp32 in -> bf16 out ----------------
__global__ __launch_bounds__(256) void ln_kernel(const float* __restrict__ x,
                                                 const float* __restrict__ scale,
                                                 const float* __restrict__ bias,
                                                 u16* __restrict__ out) {
    int row = blockIdx.x;
    int t = threadIdx.x;
    const float* xr = x + (size_t)row * D_MODEL;
    float4 v = ((const float4*)xr)[t];
    float s  = v.x + v.y + v.z + v.w;
    float ss = v.x*v.x + v.y*v.y + v.z*v.z + v.w*v.w;
    #pragma unroll
    for (int off = 1; off < 64; off <<= 1) {
        s  += __shfl_xor(s, off);
        ss += __shfl_xor(ss, off);
    }
    __shared__ float red[8];
    int wave = t >> 6, lane = t & 63;
    if (lane == 0) { red[wave] = s; red[4 + wave] = ss; }
    __syncthreads();
    float S  = red[0] + red[1] + red[2] + red[3];
    float SS = red[4] + red[5] + red[6] + red[7];
    float mu  = S * (1.0f / D_MODEL);
    float var = SS * (1.0f / D_MODEL) - mu * mu;
    float r = rsqrtf(var + 1e-5f);
    float4 sc = ((const float4*)scale)[t];
    float4 bi = ((const float4*)bias)[t];
    ushort4 o;
    o.x = f2bf((v.x - mu) * r * sc.x + bi.x);
    o.y = f2bf((v.y - mu) * r * sc.y + bi.y);
    o.z = f2bf((v.z - mu) * r * sc.z + bi.z);
    o.w = f2bf((v.w - mu) * r * sc.w + bi.w);
    ((ushort4*)(out + (size_t)row * D_MODEL))[t] = o;
}

// ---------------- bf16 MFMA GEMM: r2's verified best (256-row tile, D-ring, counted vmcnt) ----
// C[M,N] = A[M,K] * W[N,K]^T + epilogue. 8 waves (2 token-rows x 4 col-groups);
// wave tile 128 x (BN_/4); BK=32. LDS swizzle (64B rows): chunk-slot c' of row
// r holds global chunk c' ^ ((r>>1)&3) -> conflict-free (r2: conflicts=0).
// Bijective XCD-chunked block remap (r2: FETCH 297->84MB). Pipeline: compute
// K-tile t from slot t%D while staging t+D-1 into slot (t+D-1)%D; ONE counted
// vmcnt per K-tile ((RA+RB)*(D-2)) -> tile t+1 landed, newest D-2 batches stay
// in flight across barriers (never drained). Best measured GEMM config: FC2=95us.
template<int MODE, int BN_, int NPH, int DEPTH>
__global__ __launch_bounds__(512, 2) void gemm_kernel(
        const u16* __restrict__ A, const u16* __restrict__ W,
        const float* __restrict__ bias, const float* __restrict__ res,
        void* __restrict__ outp, void* __restrict__ out2, int M, int N, int K) {
    constexpr int BM = 256, BK = 32;
    constexpr int NFN = BN_ / 64;          // N-frags per wave: 4 (BN=256) or 2 (BN=128)
    constexpr int RA = 2;                  // gl2lds rounds per K-tile for A
    constexpr int RB = BN_ / 128;          // for B: 2 or 1
    constexpr int S = DEPTH - 1;           // stage lead (K-tiles)
    constexpr int VST = (RA + RB) * (DEPTH - 2);
    constexpr int ASZ = BM * BK, BSZ = BN_ * BK;
    __shared__ __attribute__((aligned(16))) u16 As[DEPTH * ASZ];
    __shared__ __attribute__((aligned(16))) u16 Bs[DEPTH * BSZ];

    int t = threadIdx.x;
    int lane = t & 63, w = t >> 6;
    int lc = lane & 15, lr = lane >> 4;
    int nb = N / BN_;
    // bijective XCD-chunked remap (grid always %8==0)
    int cpx = gridDim.x >> 3;
    int blk = (blockIdx.x & 7) * cpx + (blockIdx.x >> 3);
    int bm = blk / nb, bn = blk % nb;
    int m0 = bm * BM, n0 = bn * BN_;
    int wm = (w >> 2) * 128;               // wave token-row base within tile
    int wn = (w & 3) * (BN_ / 4);          // wave col base within tile
    int cxor = (lr ^ ((lc >> 1) & 3)) * 8; // swizzled 16B-chunk select

    const u16* Abase = A + (size_t)m0 * K;
    const u16* Bbase = W + (size_t)n0 * K;

    size_t aoff[RA]; int aldo[RA];
    #pragma unroll
    for (int n = 0; n < RA; ++n) {
        int q = (n * 8 + w) * 64 + lane;
        int row = q >> 2;
        aoff[n] = (size_t)row * K + (((q & 3) ^ ((row >> 1) & 3)) * 8);
        aldo[n] = (n * 8 + w) * 512;
    }
    size_t boff[RB]; int bldo[RB];
    #pragma unroll
    for (int n = 0; n < RB; ++n) {
        int q = (n * 8 + w) * 64 + lane;
        int row = q >> 2;
        boff[n] = (size_t)row * K + (((q & 3) ^ ((row >> 1) & 3)) * 8);
        bldo[n] = (n * 8 + w) * 512;
    }

    const int NT = K / BK;
    // prologue: stage tiles 0..S-1 into slots 0..S-1
    for (int u = 0; u < S; ++u) {
        size_t kk = (size_t)u * BK;
        #pragma unroll
        for (int n = 0; n < RA; ++n) gl2lds16(Abase + aoff[n] + kk, &As[u * ASZ + aldo[n]]);
        #pragma unroll
        for (int n = 0; n < RB; ++n) gl2lds16(Bbase + boff[n] + kk, &Bs[u * BSZ + bldo[n]]);
    }
    vwait<VST>();
    bar();

    f4v acc[8][NFN] = {};
    int cur = 0, sb = S % DEPTH;

    for (int kt = 0; kt < NT; ++kt) {
        const u16* Ab = &As[cur * ASZ];
        const u16* Bb = &Bs[cur * BSZ];
        u16* Asb = &As[sb * ASZ];
        u16* Bsb = &Bs[sb * BSZ];
        int kts = kt + S; if (kts >= NT) kts = NT - 1;   // clamped dummy at tail
        size_t kk = (size_t)kts * BK;

        // ---- phase 0: A-frags + B-frags 0,1 ; stage A(t+S) ----
        s8v af[8];
        #pragma unroll
        for (int i = 0; i < 8; ++i)
            af[i] = *(const s8v*)&Ab[(wm + i * 16 + lc) * BK + cxor];
        s8v b0 = *(const s8v*)&Bb[(wn + lc) * BK + cxor];
        s8v b1 = *(const s8v*)&Bb[(wn + 16 + lc) * BK + cxor];
        #pragma unroll
        for (int n = 0; n < RA; ++n) gl2lds16(Abase + aoff[n] + kk, Asb + aldo[n]);
        if constexpr (NPH == 1) {
            #pragma unroll
            for (int n = 0; n < RB; ++n) gl2lds16(Bbase + boff[n] + kk, Bsb + bldo[n]);
        }
        bar();
        __builtin_amdgcn_s_setprio(1);
        #pragma unroll
        for (int i = 0; i < 8; ++i) {
            if constexpr (MODE == 4) {
                acc[i][0] = __builtin_amdgcn_mfma_f32_16x16x32_bf16(af[i], b0, acc[i][0], 0, 0, 0);
                acc[i][1] = __builtin_amdgcn_mfma_f32_16x16x32_bf16(af[i], b1, acc[i][1], 0, 0, 0);
            } else {  // swapped: D.row = W-col, D.col = token
                acc[i][0] = __builtin_amdgcn_mfma_f32_16x16x32_bf16(b0, af[i], acc[i][0], 0, 0, 0);
                acc[i][1] = __builtin_amdgcn_mfma_f32_16x16x32_bf16(b1, af[i], acc[i][1], 0, 0, 0);
            }
        }
        __builtin_amdgcn_s_setprio(0);
        if constexpr (NPH == 1) vwait<VST>();
        bar();

        if constexpr (NPH == 2) {
            // ---- phase 1: B-frags 2,3 (A reused) ; stage B(t+S) ----
            s8v b2 = *(const s8v*)&Bb[(wn + 32 + lc) * BK + cxor];
            s8v b3 = *(const s8v*)&Bb[(wn + 48 + lc) * BK + cxor];
            #pragma unroll
            for (int n = 0; n < RB; ++n) gl2lds16(Bbase + boff[n] + kk, Bsb + bldo[n]);
            bar();
            __builtin_amdgcn_s_setprio(1);
            #pragma unroll
            for (int i = 0; i < 8; ++i) {
                if constexpr (MODE == 4) {
                    acc[i][2] = __builtin_amdgcn_mfma_f32_16x16x32_bf16(af[i], b2, acc[i][2], 0, 0, 0);
                    acc[i][3] = __builtin_amdgcn_mfma_f32_16x16x32_bf16(af[i], b3, acc[i][3], 0, 0, 0);
                } else {
                    acc[i][2] = __builtin_amdgcn_mfma_f32_16x16x32_bf16(b2, af[i], acc[i][2], 0, 0, 0);
                    acc[i][3] = __builtin_amdgcn_mfma_f32_16x16x32_bf16(b3, af[i], acc[i][3], 0, 0, 0);
                }
            }
            __builtin_amdgcn_s_setprio(0);
            vwait<VST>();
            bar();
        }
        cur = (cur + 1 == DEPTH) ? 0 : cur + 1;
        sb  = (sb + 1 == DEPTH) ? 0 : sb + 1;
    }

    if constexpr (MODE == 4) {
        #pragma unroll
        for (int i = 0; i < 8; ++i) {
            #pragma unroll
            for (int j = 0; j < NFN; ++j) {
                int col = n0 + wn + j * 16 + lc;
                int colbase = n0 + wn + j * 16;   // wave-uniform segment select
                if (colbase < 2048) {
                    float sc = (colbase < 1024) ? QSCALE : 1.0f;
                    #pragma unroll
                    for (int r = 0; r < 4; ++r) {
                        int row = m0 + wm + i * 16 + lr * 4 + r;
                        ((u16*)outp)[(size_t)row * 2048 + col] = f2bf(acc[i][j][r] * sc);
                    }
                } else {
                    // V: write transposed to vt[bh*64+d][t], 4 consecutive t packed
                    int dlin = col - 2048;
                    int h = dlin >> 6, dd = dlin & 63;
                    int trow = m0 + wm + i * 16 + lr * 4;
                    int bb = trow >> 11, tt = trow & 2047;
                    int bh = bb * 16 + h;
                    ushort4 vv;
                    vv.x = f2bf(acc[i][j][0]); vv.y = f2bf(acc[i][j][1]);
                    vv.z = f2bf(acc[i][j][2]); vv.w = f2bf(acc[i][j][3]);
                    *(ushort4*)&((u16*)out2)[((size_t)bh * 64 + dd) * SEQ + tt] = vv;
                }
            }
        }
    } else {
        // swapped layout: lane lc owns row = wm+i*16+lc, 4 consecutive cols at lr*4
        #pragma unroll
        for (int j = 0; j < NFN; ++j) {
            int colb = n0 + wn + j * 16 + lr * 4;
            float4 b4;
            if constexpr (MODE != 1) b4 = *(const float4*)&bias[colb];
            #pragma unroll
            for (int i = 0; i < 8; ++i) {
                int row = m0 + wm + i * 16 + lc;
                size_t idx = (size_t)row * N + colb;
                f4v a = acc[i][j];
                if constexpr (MODE == 2) {
                    ushort4 o;
                    o.x = f2bf(gelu_fast(a[0] + b4.x));
                    o.y = f2bf(gelu_fast(a[1] + b4.y));
                    o.z = f2bf(gelu_fast(a[2] + b4.z));
                    o.w = f2bf(gelu_fast(a[3] + b4.w));
                    *(ushort4*)&((u16*)outp)[idx] = o;
                } else {
                    float4 rr = *(const float4*)&res[idx];
                    float4 o;
                    if constexpr (MODE == 3) {
                        o.x = rr.x + a[0] + b4.x; o.y = rr.y + a[1] + b4.y;
                        o.z = rr.z + a[2] + b4.z; o.w = rr.w + a[3] + b4.w;
                    } else {
                        o.x = rr.x + a[0]; o.y = rr.y + a[1];
                        o.z = rr.z + a[2]; o.w = rr.w + a[3];
                    }
                    *(float4*)&((float*)outp)[idx] = o;
                }
            }
        }
    }
}

// ---------------- flash attention, 32x32x16 MFMA (r4's permlane version, verified) ----------------
// P transpose fully in-register via permlane32_swap: no Ps LDS buffer, no bank
// conflicts, LDS 16.9KB.
__global__ __launch_bounds__(256) void attn_kernel(const u16* __restrict__ qk,
                                                   const u16* __restrict__ vt,
                                                   u16* __restrict__ out) {
    __shared__ __attribute__((aligned(16))) u16 Ks[64 * 64];   // [key][d], swizzled chunks
    __shared__ __attribute__((aligned(16))) u16 Vts[64 * 64];  // [d][key], swizzled chunks
    __shared__ float l_s[128];
    int t = threadIdx.x, lane = t & 63, w = t >> 6;
    int l31 = lane & 31, hi = lane >> 5;
    int blk = blockIdx.x;
    int bh = blk & 63, qt = blk >> 6;    // XCD swizzle: same head -> same XCD
    int b = bh >> 4, h = bh & 15;
    size_t tok0 = (size_t)b * SEQ;
    int q0 = qt * 128;

    // Q B-operand frags in registers: B[n=q=l31][k=hi*8+j], 4 d-chunks of 16
    s8v bq[4];
    {
        const u16* qp = qk + (tok0 + q0 + w * 32 + l31) * 2048 + h * 64 + hi * 8;
        #pragma unroll
        for (int dch = 0; dch < 4; ++dch) bq[dch] = *(const s8v*)(qp + dch * 16);
    }
    f16v o[2] = {};
    float lp = 0.f;

    int srow[2], scg[2];
    #pragma unroll
    for (int n = 0; n < 2; ++n) {
        int chunk = (w * 2 + n) * 64 + lane;
        srow[n] = chunk >> 3;
        scg[n]  = ((chunk & 7) ^ (srow[n] & 7)) * 8;
    }
    const u16* vbase = vt + (size_t)bh * 64 * SEQ;

    for (int kt = 0; kt < SEQ / 64; ++kt) {
        #pragma unroll
        for (int n = 0; n < 2; ++n) {
            gl2lds16(&qk[(tok0 + kt * 64 + srow[n]) * 2048 + 1024 + h * 64 + scg[n]],
                     &Ks[(w * 2 + n) * 512]);
            gl2lds16(&vbase[(size_t)srow[n] * SEQ + kt * 64 + scg[n]],
                     &Vts[(w * 2 + n) * 512]);
        }
        __syncthreads();

        // S^T = K Q'^T : two 32-key blocks; D: lane=q, reg r -> key rr+8g+4hi
        f16v s_[2] = {};
        #pragma unroll
        for (int kb = 0; kb < 2; ++kb)
            #pragma unroll
            for (int dch = 0; dch < 4; ++dch) {
                s8v ak = *(const s8v*)&Ks[(kb * 32 + l31) * 64 + ((dch * 2 + hi) ^ (l31 & 7)) * 8];
                s_[kb] = __builtin_amdgcn_mfma_f32_32x32x16_bf16(ak, bq[dch], s_[kb], 0, 0, 0);
            }

        // p = 2^s (Schraudolph bits) -> packed bf16 pairs in registers
        u2v pk[2][4];
        #pragma unroll
        for (int kb = 0; kb < 2; ++kb)
            #pragma unroll
            for (int g = 0; g < 4; ++g) {
                u32 ib[4];
                #pragma unroll
                for (int rr = 0; rr < 4; ++rr) {
                    ib[rr] = (u32)fmaf(s_[kb][g * 4 + rr], 8388608.0f, 1064992506.0f);
                    lp += __builtin_bit_cast(float, ib[rr]);
                }
                pk[kb][g][0] = __builtin_amdgcn_perm(ib[1], ib[0], 0x07060302);
                pk[kb][g][1] = __builtin_amdgcn_perm(ib[3], ib[2], 0x07060302);
            }

        // O += P V : per ch, 2 permlane32_swap deliver both A-frag halves
        #pragma unroll
        for (int ch = 0; ch < 4; ++ch) {
            int kb = ch >> 1, a2 = (ch & 1) * 2;
            u2v sx = __builtin_amdgcn_permlane32_swap(pk[kb][a2][0], pk[kb][a2 + 1][0], false, false);
            u2v sy = __builtin_amdgcn_permlane32_swap(pk[kb][a2][1], pk[kb][a2 + 1][1], false, false);
            u4v tmp; tmp.x = sx[0]; tmp.y = sy[0]; tmp.z = sx[1]; tmp.w = sy[1];
            s8v ap = __builtin_bit_cast(s8v, tmp);
            #pragma unroll
            for (int dblk = 0; dblk < 2; ++dblk) {
                s8v bv = *(const s8v*)&Vts[(dblk * 32 + l31) * 64 + ((ch * 2 + hi) ^ (l31 & 7)) * 8];
                o[dblk] = __builtin_amdgcn_mfma_f32_32x32x16_bf16(ap, bv, o[dblk], 0, 0, 0);
            }
        }
        __syncthreads();   // guard Ks/Vts overwrite by next tile's staging
    }

    lp += __shfl_xor(lp, 32);
    l_s[w * 32 + l31] = 1.0f / lp;
    #pragma unroll
    for (int r = 0; r < 16; ++r) {
        int qrl = (r & 3) + 8 * (r >> 2) + 4 * hi;
        float linv = l_s[w * 32 + qrl];
        size_t row = tok0 + q0 + w * 32 + qrl;
        #pragma unroll
        for (int dblk = 0; dblk < 2; ++dblk)
            out[row * 1024 + h * 64 + dblk * 32 + l31] = f2bf(o[dblk][r] * linv);
    }
}

// ---------------- launch ----------------
extern "C" void kernel_launch(void* const* d_in, const int* in_sizes, int n_in,
                              void* d_out, int out_size, void* d_ws, size_t ws_size,
                              hipStream_t stream) {
    const float* x      = (const float*)d_in[0];
    const float* ln1_s  = (const float*)d_in[1];
    const float* ln1_b  = (const float*)d_in[2];
    const float* qkv_w  = (const float*)d_in[3];
    const float* out_w  = (const float*)d_in[4];
    const float* ln2_s  = (const float*)d_in[5];
    const float* ln2_b  = (const float*)d_in[6];
    const float* fc1_w  = (const float*)d_in[7];
    const float* fc1_b  = (const float*)d_in[8];
    const float* fc2_w  = (const float*)d_in[9];
    const float* fc2_b  = (const float*)d_in[10];
    float* out = (float*)d_out;

    char* ws = (char*)d_ws;
    size_t off = 0;
    auto alloc = [&](size_t bytes) -> void* {
        void* p = ws + off;
        off += (bytes + 255) & ~(size_t)255;
        return p;
    };
    u16* wq  = (u16*)alloc((size_t)3072 * 1024 * 2);   // wq|wo|w1|w2 contiguous
    u16* wo  = (u16*)alloc((size_t)1024 * 1024 * 2);
    u16* w1  = (u16*)alloc((size_t)4096 * 1024 * 2);
    u16* w2  = (u16*)alloc((size_t)1024 * 4096 * 2);
    u16* h1  = (u16*)alloc((size_t)TOKENS * 1024 * 2);   // aliased later as attn_out
    u16* qk  = (u16*)alloc((size_t)TOKENS * 2048 * 2);   // Q' | K ; aliased later as h2
    float* x2 = (float*)alloc((size_t)TOKENS * 1024 * 4);
    u16* g   = (u16*)alloc((size_t)TOKENS * 4096 * 2);
    u16* attn_out = h1;        // h1 dead after QKV GEMM
    u16* h2       = qk;        // qk dead after attention
    u16* vt       = (u16*)x2;  // vt (16MB) dead before x2 (32MB) is written
    (void)wo; (void)w1; (void)w2;

    cvt_all_kernel<<<(N4_QKV + N4_WO + 2 * N4_FC) / 256, 256, 0, stream>>>(
        qkv_w, out_w, fc1_w, fc2_w, wq);

    // LN1
    ln_kernel<<<TOKENS, 256, 0, stream>>>(x, ln1_s, ln1_b, h1);
    // QKV projection: 256x256 tiles, depth-4 ring (grid 384)
    gemm_kernel<4, 256, 2, 4><<<(TOKENS / 256) * (3072 / 256), 512, 0, stream>>>(
        h1, wq, nullptr, nullptr, qk, vt, TOKENS, 3072, 1024);
    // attention
    attn_kernel<<<64 * 16, 256, 0, stream>>>(qk, vt, attn_out);
    // out projection + residual: 256x128 tiles, depth-6 ring (grid 256)
    gemm_kernel<1, 128, 1, 6><<<(TOKENS / 256) * (1024 / 128), 512, 0, stream>>>(
        attn_out, wo, nullptr, x, x2, nullptr, TOKENS, 1024, 1024);
    // LN2
    ln_kernel<<<TOKENS, 256, 0, stream>>>(x2, ln2_s, ln2_b, h2);
    // FC1 + bias + fast GELU (grid 512)
    gemm_kernel<2, 256, 2, 4><<<(TOKENS / 256) * (DIMFF / 256), 512, 0, stream>>>(
        h2, w1, fc1_b, nullptr, g, nullptr, TOKENS, DIMFF, 1024);
    // FC2 + bias + residual (grid 256)
    gemm_kernel<3, 128, 1, 6><<<(TOKENS / 256) * (1024 / 128), 512, 0, stream>>>(
        g, w2, fc2_b, x2, out, nullptr, TOKENS, 1024, DIMFF);
}